// Round 8
// baseline (333.723 us; speedup 1.0000x reference)
//
#include <hip/hip_runtime.h>
#include <hip/hip_bf16.h>
#include <cstdint>
#include <cstddef>

// ---------------------------------------------------------------------------
// GraphAutoEncoder: 3x TAGConv(K=3) + linear + bilinear decode.
// N=10000, E=320000, D: 256 -> 128 -> 128 -> 64.
// Round 7: fused {final-Horner-agg -> next proj} kernels (F1,F2,F3): the
// combine+ReLU rows stay in LDS and feed MFMA directly; layer-1 proj reads
// fp32 x directly. 15 dispatches.
// ---------------------------------------------------------------------------

typedef __attribute__((ext_vector_type(8)))  short short8;   // 8 bf16
typedef __attribute__((ext_vector_type(4)))  float f32x4;
typedef __attribute__((ext_vector_type(16))) float f32x16;

static __device__ __forceinline__ ushort f2bf(float f) {
    __hip_bfloat16 h = __float2bfloat16(f);
    return *reinterpret_cast<const ushort*>(&h);
}
static __device__ __forceinline__ float bf2f(ushort u) {
    union { uint i; float f; } v; v.i = ((uint)u) << 16; return v.f;
}

// ---------------- setup: edge count + all weight prep (fused) ----------

static __device__ __forceinline__ void prep_w_elem(const float* W, ushort* Wp,
                                                   int DIN, int DOUT, int i) {
    int hp  = i / (DIN * DOUT);
    int rem = i - hp * DIN * DOUT;
    int d   = rem / DOUT;
    int o   = rem - d * DOUT;
    Wp[(size_t)(hp * DOUT + o) * DIN + d] = f2bf(W[i]);
}
static __device__ __forceinline__ void prep_wt_elem(const float* W, ushort* Wt,
                                                    int K, int C, int i) {
    int k = i / C, c = i - k * C;
    Wt[(size_t)c * K + k] = f2bf(W[i]);
}

__global__ void setup_kernel(const int* __restrict__ dst, int* __restrict__ counts, int E,
                             const float* __restrict__ W1, ushort* __restrict__ Wp1,
                             const float* __restrict__ W2, ushort* __restrict__ Wp2,
                             const float* __restrict__ W3, ushort* __restrict__ Wp3,
                             const float* __restrict__ Wf, ushort* __restrict__ Wfb,
                             const float* __restrict__ Wd, ushort* __restrict__ Wdb) {
    const int n1 = 4 * 256 * 128, n2 = 4 * 128 * 128, n3 = 4 * 128 * 64, nf = 64 * 64;
    int i = blockIdx.x * blockDim.x + threadIdx.x;
    if (i < E) atomicAdd(&counts[dst[i]], 1);
    if (i < n1) { prep_w_elem(W1, Wp1, 256, 128, i); return; }
    int j = i - n1;
    if (j < n2) { prep_w_elem(W2, Wp2, 128, 128, j); return; }
    j -= n2;
    if (j < n3) { prep_w_elem(W3, Wp3, 128, 64, j); return; }
    j -= n3;
    if (j < nf) { prep_wt_elem(Wf, Wfb, 64, 64, j); return; }
    j -= nf;
    if (j < nf) { prep_wt_elem(Wd, Wdb, 64, 64, j); return; }
}

// exclusive scan counts[n] -> rowstart[n+1], plus dis[i] = rsqrt(deg) fused
__global__ void scan_kernel(const int* __restrict__ counts, int* __restrict__ rowstart,
                            float* __restrict__ dis, int n) {
    __shared__ int sums[1024];
    int t = threadIdx.x;
    int chunk = (n + 1023) / 1024;
    int base = t * chunk;
    int s = 0;
    for (int i = 0; i < chunk; ++i) {
        int idx = base + i;
        if (idx < n) s += counts[idx];
    }
    sums[t] = s;
    __syncthreads();
    for (int off = 1; off < 1024; off <<= 1) {
        int v = (t >= off) ? sums[t - off] : 0;
        __syncthreads();
        sums[t] += v;
        __syncthreads();
    }
    int run = sums[t] - s;
    for (int i = 0; i < chunk; ++i) {
        int idx = base + i;
        if (idx < n) {
            rowstart[idx] = run;
            int c = counts[idx];
            dis[idx] = (c > 0) ? rsqrtf((float)c) : 0.f;
            run += c;
        }
    }
    if (t == 1023) rowstart[n] = sums[1023];
}

// CSR fill, interleaved int2 (src, float_bits(w)); w = dis[src]*dis[dst]
__global__ void csr_fill_kernel(const int* __restrict__ src, const int* __restrict__ dst,
                                const float* __restrict__ dis, const int* __restrict__ rowstart,
                                int* __restrict__ cursor, int2* __restrict__ csr2, int E) {
    int e = blockIdx.x * blockDim.x + threadIdx.x;
    if (e < E) {
        int d = dst[e];
        int s = src[e];
        int pos = rowstart[d] + atomicAdd(&cursor[d], 1);
        csr2[pos] = make_int2(s, __float_as_int(dis[s] * dis[d]));
    }
}

// ---------------- shared gather core (pipelined) ----------------------------
template <int D>
static __device__ __forceinline__ void agg_gather(
        const ushort* __restrict__ h, const int2* __restrict__ csr2,
        int beg, int end, int lane, int sub, int ll, float acc[8]) {
    constexpr int LPE = D / 8;
    constexpr int EPI = 64 / LPE;
    for (int j0 = beg; j0 < end; j0 += 64) {
        int take = end - j0;
        if (take > 64) take = 64;
        int2 ed = make_int2(0, 0);
        if (lane < take) ed = csr2[j0 + lane];
        int   s = ed.x;
        float w = __int_as_float(ed.y);
        int tt = (take + EPI - 1) & ~(EPI - 1);

        float wc = __shfl(w, sub);
        int   sc = __shfl(s, sub);
        short8 hv = *(const short8*)(h + (size_t)sc * D + ll * 8);
        for (int i = EPI; i < tt; i += EPI) {
            float wn = __shfl(w, i + sub);
            int   sn = __shfl(s, i + sub);
            short8 hn = *(const short8*)(h + (size_t)sn * D + ll * 8);
            #pragma unroll
            for (int v = 0; v < 8; ++v)
                acc[v] = fmaf(wc, bf2f((ushort)hv[v]), acc[v]);
            wc = wn; hv = hn;
        }
        #pragma unroll
        for (int v = 0; v < 8; ++v)
            acc[v] = fmaf(wc, bf2f((ushort)hv[v]), acc[v]);
    }
}

// ---------------- Horner aggregation (standalone, mid-chain) ---------------
// out = yk + A*h ; 512-thr blocks, wave-per-node.
template <int D, bool RELU>
__global__ __launch_bounds__(512) void agg6_kernel(
        const ushort* __restrict__ h, const ushort* __restrict__ yk,
        const int* __restrict__ rowstart, const int2* __restrict__ csr2,
        ushort* __restrict__ out, int Nn) {
    constexpr int LPE = D / 8;
    int wave = threadIdx.x >> 6, lane = threadIdx.x & 63;
    int n = blockIdx.x * 8 + wave;
    if (n >= Nn) return;
    int sub = lane / LPE;
    int ll  = lane % LPE;

    float acc[8];
    #pragma unroll
    for (int v = 0; v < 8; ++v) acc[v] = 0.f;
    agg_gather<D>(h, csr2, rowstart[n], rowstart[n + 1], lane, sub, ll, acc);

    #pragma unroll
    for (int off = LPE; off < 64; off <<= 1) {
        #pragma unroll
        for (int v = 0; v < 8; ++v) acc[v] += __shfl_xor(acc[v], off);
    }

    if (sub == 0) {
        short8 yv = *(const short8*)(yk + (size_t)n * D + ll * 8);
        short8 o;
        #pragma unroll
        for (int v = 0; v < 8; ++v) {
            float val = acc[v] + bf2f((ushort)yv[v]);
            if (RELU) val = fmaxf(val, 0.f);
            o[v] = (short)f2bf(val);
        }
        *(short8*)(out + (size_t)n * D + ll * 8) = o;
    }
}

// ---------------- fused: final Horner step (relu) -> next-layer proj --------
// Block = 512 thr = 8 waves, 32 nodes. Phase A: wave w aggregates nodes
// w*4..w*4+3 (relu(y0 + A h)) into LDS. Phase B: wave w projects hop (w&3),
// row-half (w>>2): y[hp] = rows @ W[hp]^T (+bias on hop 0).
template <int DIN, int DOUT>
__global__ __launch_bounds__(512) void fused_agg_proj_kernel(
        const ushort* __restrict__ h, const ushort* __restrict__ y0,
        const int* __restrict__ rowstart, const int2* __restrict__ csr2,
        const ushort* __restrict__ Wp, const float* __restrict__ bias,
        ushort* __restrict__ y, int Nn) {
    __shared__ ushort sh[32][DIN + 8];
    constexpr int LPE = DIN / 8;
    int wave = threadIdx.x >> 6, lane = threadIdx.x & 63;
    int nb0 = blockIdx.x * 32;
    int sub = lane / LPE, ll = lane % LPE;

    // phase A: aggregate 4 nodes per wave
    for (int c = 0; c < 4; ++c) {
        int nl = wave * 4 + c;
        int nc = min(nb0 + nl, Nn - 1);
        float acc[8];
        #pragma unroll
        for (int v = 0; v < 8; ++v) acc[v] = 0.f;
        agg_gather<DIN>(h, csr2, rowstart[nc], rowstart[nc + 1], lane, sub, ll, acc);
        #pragma unroll
        for (int off = LPE; off < 64; off <<= 1) {
            #pragma unroll
            for (int v = 0; v < 8; ++v) acc[v] += __shfl_xor(acc[v], off);
        }
        if (sub == 0) {
            short8 yv = *(const short8*)(y0 + (size_t)nc * DIN + ll * 8);
            short8 o;
            #pragma unroll
            for (int v = 0; v < 8; ++v)
                o[v] = (short)f2bf(fmaxf(acc[v] + bf2f((ushort)yv[v]), 0.f));
            *(short8*)&sh[nl][ll * 8] = o;
        }
    }
    __syncthreads();

    // phase B: projection from LDS
    constexpr int NJ = DOUT / 16;
    int hp = wave & 3, half = wave >> 2;
    int lr = lane & 15, lk = lane >> 4;

    f32x4 pacc[NJ];
    #pragma unroll
    for (int nj = 0; nj < NJ; ++nj) pacc[nj] = (f32x4){0.f, 0.f, 0.f, 0.f};

    #pragma unroll
    for (int kc = 0; kc < DIN; kc += 32) {
        short8 a = *(const short8*)&sh[half * 16 + lr][kc + lk * 8];
        #pragma unroll
        for (int nj = 0; nj < NJ; ++nj) {
            short8 b = *(const short8*)(Wp + (size_t)(hp * DOUT + nj * 16 + lr) * DIN
                                        + kc + lk * 8);
            pacc[nj] = __builtin_amdgcn_mfma_f32_16x16x32_bf16(a, b, pacc[nj], 0, 0, 0);
        }
    }

    ushort* yw = y + (size_t)hp * Nn * DOUT;
    #pragma unroll
    for (int nj = 0; nj < NJ; ++nj) {
        int cc = nj * 16 + lr;
        float bv = (hp == 0) ? bias[cc] : 0.f;
        int rbase = nb0 + half * 16 + lk * 4;
        #pragma unroll
        for (int r = 0; r < 4; ++r) {
            int row = rbase + r;
            if (row < Nn)
                yw[(size_t)row * DOUT + cc] = f2bf(pacc[nj][r] + bv);
        }
    }
}

// ---------------- fused: final Horner step (relu) -> zz,zw projections ------
__global__ __launch_bounds__(512) void fused_agg_lin_kernel(
        const ushort* __restrict__ h, const ushort* __restrict__ y0,
        const int* __restrict__ rowstart, const int2* __restrict__ csr2,
        const ushort* __restrict__ Wfb, const float* __restrict__ bias,
        const ushort* __restrict__ Wdb,
        ushort* __restrict__ zz, ushort* __restrict__ zw, int Nn) {
    __shared__ ushort sh[32][72];
    __shared__ ushort sh2[32][72];
    constexpr int DIN = 64, LPE = 8;
    int wave = threadIdx.x >> 6, lane = threadIdx.x & 63;
    int nb0 = blockIdx.x * 32;
    int sub = lane / LPE, ll = lane % LPE;

    for (int c = 0; c < 4; ++c) {
        int nl = wave * 4 + c;
        int nc = min(nb0 + nl, Nn - 1);
        float acc[8];
        #pragma unroll
        for (int v = 0; v < 8; ++v) acc[v] = 0.f;
        agg_gather<DIN>(h, csr2, rowstart[nc], rowstart[nc + 1], lane, sub, ll, acc);
        #pragma unroll
        for (int off = LPE; off < 64; off <<= 1) {
            #pragma unroll
            for (int v = 0; v < 8; ++v) acc[v] += __shfl_xor(acc[v], off);
        }
        if (sub == 0) {
            short8 yv = *(const short8*)(y0 + (size_t)nc * DIN + ll * 8);
            short8 o;
            #pragma unroll
            for (int v = 0; v < 8; ++v)
                o[v] = (short)f2bf(fmaxf(acc[v] + bf2f((ushort)yv[v]), 0.f));
            *(short8*)&sh[nl][ll * 8] = o;
        }
    }
    __syncthreads();

    int lr = lane & 15, lk = lane >> 4;
    // pass 1: zz = sh @ Wf^T + bf (wave 0 only; 32 rows)
    if (wave == 0) {
        short8 a[2][2], b[4][2];
        #pragma unroll
        for (int kc = 0; kc < 2; ++kc) {
            a[0][kc] = *(const short8*)&sh[lr][kc * 32 + lk * 8];
            a[1][kc] = *(const short8*)&sh[16 + lr][kc * 32 + lk * 8];
            #pragma unroll
            for (int nj = 0; nj < 4; ++nj)
                b[nj][kc] = *(const short8*)(Wfb + (size_t)(nj * 16 + lr) * 64 + kc * 32 + lk * 8);
        }
        f32x4 acc1[2][4];
        #pragma unroll
        for (int mi = 0; mi < 2; ++mi)
            #pragma unroll
            for (int nj = 0; nj < 4; ++nj) {
                acc1[mi][nj] = (f32x4){0.f, 0.f, 0.f, 0.f};
                acc1[mi][nj] = __builtin_amdgcn_mfma_f32_16x16x32_bf16(a[mi][0], b[nj][0], acc1[mi][nj], 0, 0, 0);
                acc1[mi][nj] = __builtin_amdgcn_mfma_f32_16x16x32_bf16(a[mi][1], b[nj][1], acc1[mi][nj], 0, 0, 0);
            }
        #pragma unroll
        for (int nj = 0; nj < 4; ++nj) {
            int cc = nj * 16 + lr;
            float bv = bias[cc];
            #pragma unroll
            for (int mi = 0; mi < 2; ++mi) {
                int rloc = mi * 16 + lk * 4;
                #pragma unroll
                for (int r = 0; r < 4; ++r) {
                    ushort u = f2bf(acc1[mi][nj][r] + bv);
                    sh2[rloc + r][cc] = u;
                    int row = nb0 + rloc + r;
                    if (row < Nn) zz[(size_t)row * 64 + cc] = u;
                }
            }
        }
    }
    __syncthreads();
    // pass 2: zw = zz @ Wd^T
    if (wave == 0) {
        short8 a2[2][2], b2[4][2];
        #pragma unroll
        for (int kc = 0; kc < 2; ++kc) {
            a2[0][kc] = *(const short8*)&sh2[lr][kc * 32 + lk * 8];
            a2[1][kc] = *(const short8*)&sh2[16 + lr][kc * 32 + lk * 8];
            #pragma unroll
            for (int nj = 0; nj < 4; ++nj)
                b2[nj][kc] = *(const short8*)(Wdb + (size_t)(nj * 16 + lr) * 64 + kc * 32 + lk * 8);
        }
        f32x4 acc2[2][4];
        #pragma unroll
        for (int mi = 0; mi < 2; ++mi)
            #pragma unroll
            for (int nj = 0; nj < 4; ++nj) {
                acc2[mi][nj] = (f32x4){0.f, 0.f, 0.f, 0.f};
                acc2[mi][nj] = __builtin_amdgcn_mfma_f32_16x16x32_bf16(a2[mi][0], b2[nj][0], acc2[mi][nj], 0, 0, 0);
                acc2[mi][nj] = __builtin_amdgcn_mfma_f32_16x16x32_bf16(a2[mi][1], b2[nj][1], acc2[mi][nj], 0, 0, 0);
            }
        #pragma unroll
        for (int nj = 0; nj < 4; ++nj) {
            int cc = nj * 16 + lr;
            #pragma unroll
            for (int mi = 0; mi < 2; ++mi) {
                int rbase = nb0 + mi * 16 + lk * 4;
                #pragma unroll
                for (int r = 0; r < 4; ++r) {
                    int row = rbase + r;
                    if (row < Nn) zw[(size_t)row * 64 + cc] = f2bf(acc2[mi][nj][r]);
                }
            }
        }
    }
}

// ---------------- layer-1 projection: fp32 x in, bf16 frags in-register -----
__global__ __launch_bounds__(256) void proj_gemm_x_kernel(
        const float* __restrict__ A, const ushort* __restrict__ Wp,
        const float* __restrict__ bias, ushort* __restrict__ y, int M) {
    constexpr int DIN = 256, DOUT = 128, NJ = 8;
    int tid = threadIdx.x, wave = tid >> 6, lane = tid & 63;
    int lr = lane & 15, lk = lane >> 4;
    int r0 = blockIdx.x * 32;
    int ra0 = min(r0 + lr, M - 1);
    int ra1 = min(r0 + 16 + lr, M - 1);

    f32x4 acc[2][NJ];
    #pragma unroll
    for (int mi = 0; mi < 2; ++mi)
        #pragma unroll
        for (int nj = 0; nj < NJ; ++nj)
            acc[mi][nj] = (f32x4){0.f, 0.f, 0.f, 0.f};

    const float* a0p = A + (size_t)ra0 * DIN + lk * 8;
    const float* a1p = A + (size_t)ra1 * DIN + lk * 8;
    #pragma unroll
    for (int kc = 0; kc < DIN; kc += 32) {
        float4 f00 = *(const float4*)(a0p + kc);
        float4 f01 = *(const float4*)(a0p + kc + 4);
        float4 f10 = *(const float4*)(a1p + kc);
        float4 f11 = *(const float4*)(a1p + kc + 4);
        short8 a0, a1;
        a0[0] = (short)f2bf(f00.x); a0[1] = (short)f2bf(f00.y);
        a0[2] = (short)f2bf(f00.z); a0[3] = (short)f2bf(f00.w);
        a0[4] = (short)f2bf(f01.x); a0[5] = (short)f2bf(f01.y);
        a0[6] = (short)f2bf(f01.z); a0[7] = (short)f2bf(f01.w);
        a1[0] = (short)f2bf(f10.x); a1[1] = (short)f2bf(f10.y);
        a1[2] = (short)f2bf(f10.z); a1[3] = (short)f2bf(f10.w);
        a1[4] = (short)f2bf(f11.x); a1[5] = (short)f2bf(f11.y);
        a1[6] = (short)f2bf(f11.z); a1[7] = (short)f2bf(f11.w);
        #pragma unroll
        for (int nj = 0; nj < NJ; ++nj) {
            short8 b = *(const short8*)(Wp + (size_t)(wave * DOUT + nj * 16 + lr) * DIN
                                        + kc + lk * 8);
            acc[0][nj] = __builtin_amdgcn_mfma_f32_16x16x32_bf16(a0, b, acc[0][nj], 0, 0, 0);
            acc[1][nj] = __builtin_amdgcn_mfma_f32_16x16x32_bf16(a1, b, acc[1][nj], 0, 0, 0);
        }
    }

    ushort* yw = y + (size_t)wave * M * DOUT;
    #pragma unroll
    for (int nj = 0; nj < NJ; ++nj) {
        int c = nj * 16 + lr;
        float bv = (wave == 0) ? bias[c] : 0.f;
        #pragma unroll
        for (int mi = 0; mi < 2; ++mi) {
            int rbase = r0 + mi * 16 + lk * 4;
            #pragma unroll
            for (int r = 0; r < 4; ++r) {
                int row = rbase + r;
                if (row < M)
                    yw[(size_t)row * DOUT + c] = f2bf(acc[mi][nj][r] + bv);
            }
        }
    }
}

// ---------------- decode: adj = ZW @ Z^T via 32x32x16 MFMA ----------------
__global__ __launch_bounds__(256) void decode32_kernel(
        const ushort* __restrict__ ZW, const ushort* __restrict__ Z,
        float* __restrict__ out, int Nn) {
    int tid = threadIdx.x, wave = tid >> 6, lane = tid & 63;
    int wr = wave >> 1, wc = wave & 1;
    int row0 = blockIdx.y * 128 + wr * 64;
    int col0 = blockIdx.x * 128 + wc * 64;
    int lr = lane & 31, hi = lane >> 5;

    short8 a[2][4], b[2][4];
    #pragma unroll
    for (int mi = 0; mi < 2; ++mi) {
        int ra = min(row0 + mi * 32 + lr, Nn - 1);
        int rb = min(col0 + mi * 32 + lr, Nn - 1);
        const ushort* pa = ZW + (size_t)ra * 64 + hi * 8;
        const ushort* pb = Z  + (size_t)rb * 64 + hi * 8;
        #pragma unroll
        for (int kc = 0; kc < 4; ++kc) {
            a[mi][kc] = *(const short8*)(pa + kc * 16);
            b[mi][kc] = *(const short8*)(pb + kc * 16);
        }
    }

    f32x16 acc[2][2];
    #pragma unroll
    for (int mi = 0; mi < 2; ++mi)
        #pragma unroll
        for (int nj = 0; nj < 2; ++nj) {
            f32x16 c;
            #pragma unroll
            for (int q = 0; q < 16; ++q) c[q] = 0.f;
            #pragma unroll
            for (int kc = 0; kc < 4; ++kc)
                c = __builtin_amdgcn_mfma_f32_32x32x16_bf16(a[mi][kc], b[nj][kc], c, 0, 0, 0);
            acc[mi][nj] = c;
        }

    bool full = (row0 + 64 <= Nn) && (col0 + 64 <= Nn);
    #pragma unroll
    for (int mi = 0; mi < 2; ++mi)
        #pragma unroll
        for (int nj = 0; nj < 2; ++nj) {
            int cb = col0 + nj * 32 + lr;
            #pragma unroll
            for (int reg = 0; reg < 16; ++reg) {
                int row = row0 + mi * 32 + (reg & 3) + 8 * (reg >> 2) + 4 * hi;
                if (full) {
                    __builtin_nontemporal_store(acc[mi][nj][reg], &out[(size_t)row * Nn + cb]);
                } else {
                    if (row < Nn && cb < Nn)
                        __builtin_nontemporal_store(acc[mi][nj][reg], &out[(size_t)row * Nn + cb]);
                }
            }
        }
}

// ---------------- launch ----------------

extern "C" void kernel_launch(void* const* d_in, const int* in_sizes, int n_in,
                              void* d_out, int out_size, void* d_ws, size_t ws_size,
                              hipStream_t stream) {
    const float* x  = (const float*)d_in[0];
    const int*   ei = (const int*)d_in[1];
    const float* W1 = (const float*)d_in[2];
    const float* b1 = (const float*)d_in[3];
    const float* W2 = (const float*)d_in[4];
    const float* b2 = (const float*)d_in[5];
    const float* W3 = (const float*)d_in[6];
    const float* b3 = (const float*)d_in[7];
    const float* Wf = (const float*)d_in[8];
    const float* bf = (const float*)d_in[9];
    const float* Wd = (const float*)d_in[10];

    const int Nn = in_sizes[0] / 256;   // 10000
    const int E  = in_sizes[1] / 2;     // 320000
    const int* src = ei;
    const int* dst = ei + E;

    char* p = (char*)d_ws;
    auto alloc = [&](size_t bytes) -> char* {
        char* r = p;
        p += (bytes + 255) & ~(size_t)255;
        return r;
    };
    size_t nslot = ((size_t)Nn * 4 + 255) & ~(size_t)255;
    int*    counts   = (int*)alloc((size_t)Nn * 4);
    int*    cursor   = (int*)alloc((size_t)Nn * 4);
    int*    rowstart = (int*)alloc((size_t)(Nn + 1) * 4);
    float*  dis      = (float*)alloc((size_t)Nn * 4);
    int2*   csr2     = (int2*)alloc((size_t)E * 8);
    ushort* yb1      = (ushort*)alloc((size_t)4 * Nn * 128 * 2);
    ushort* yb2      = (ushort*)alloc((size_t)4 * Nn * 128 * 2);
    ushort* yb3      = (ushort*)alloc((size_t)4 * Nn * 64 * 2);
    ushort* t1       = (ushort*)alloc((size_t)Nn * 128 * 2);
    ushort* t2       = (ushort*)alloc((size_t)Nn * 128 * 2);
    ushort* zzb      = (ushort*)alloc((size_t)Nn * 64 * 2);
    ushort* zwb      = (ushort*)alloc((size_t)Nn * 64 * 2);
    ushort* Wp1      = (ushort*)alloc((size_t)512 * 256 * 2);
    ushort* Wp2      = (ushort*)alloc((size_t)512 * 128 * 2);
    ushort* Wp3      = (ushort*)alloc((size_t)256 * 128 * 2);
    ushort* Wfb      = (ushort*)alloc((size_t)64 * 64 * 2);
    ushort* Wdb      = (ushort*)alloc((size_t)64 * 64 * 2);

    hipMemsetAsync(counts, 0, nslot + (size_t)Nn * 4, stream);

    int nprep = 4 * 256 * 128 + 4 * 128 * 128 + 4 * 128 * 64 + 64 * 64 + 64 * 64;
    int nsetup = nprep > E ? nprep : E;
    setup_kernel<<<(nsetup + 255) / 256, 256, 0, stream>>>(
        dst, counts, E, W1, Wp1, W2, Wp2, W3, Wp3, Wf, Wfb, Wd, Wdb);

    scan_kernel<<<1, 1024, 0, stream>>>(counts, rowstart, dis, Nn);

    int eb = (E + 255) / 256;
    csr_fill_kernel<<<eb, 256, 0, stream>>>(src, dst, dis, rowstart, cursor, csr2, E);

    int ab = (Nn + 7) / 8;              // agg blocks (8 nodes, 512 thr)
    int gb = (Nn + 31) / 32;            // proj / fused blocks (32 rows)
    size_t Y128 = (size_t)Nn * 128;
    size_t Y64  = (size_t)Nn * 64;

    // ---- layer 1: 256 -> 128 ----
    proj_gemm_x_kernel<<<gb, 256, 0, stream>>>(x, Wp1, b1, yb1, Nn);
    agg6_kernel<128, false><<<ab, 512, 0, stream>>>(yb1 + 3 * Y128, yb1 + 2 * Y128,
                                                    rowstart, csr2, t1, Nn);
    agg6_kernel<128, false><<<ab, 512, 0, stream>>>(t1, yb1 + 1 * Y128,
                                                    rowstart, csr2, t2, Nn);
    // fused: relu(y0 + A t2) -> proj layer 2
    fused_agg_proj_kernel<128, 128><<<gb, 512, 0, stream>>>(t2, yb1, rowstart, csr2,
                                                            Wp2, b2, yb2, Nn);

    // ---- layer 2: 128 -> 128 ----
    agg6_kernel<128, false><<<ab, 512, 0, stream>>>(yb2 + 3 * Y128, yb2 + 2 * Y128,
                                                    rowstart, csr2, t1, Nn);
    agg6_kernel<128, false><<<ab, 512, 0, stream>>>(t1, yb2 + 1 * Y128,
                                                    rowstart, csr2, t2, Nn);
    // fused: relu(y0 + A t2) -> proj layer 3
    fused_agg_proj_kernel<128, 64><<<gb, 512, 0, stream>>>(t2, yb2, rowstart, csr2,
                                                           Wp3, b3, yb3, Nn);

    // ---- layer 3: 128 -> 64 ----
    agg6_kernel<64, false><<<ab, 512, 0, stream>>>(yb3 + 3 * Y64, yb3 + 2 * Y64,
                                                   rowstart, csr2, t1, Nn);
    agg6_kernel<64, false><<<ab, 512, 0, stream>>>(t1, yb3 + 1 * Y64,
                                                   rowstart, csr2, t2, Nn);
    // fused: relu(y0 + A t2) -> zz, zw
    fused_agg_lin_kernel<<<gb, 512, 0, stream>>>(t2, yb3, rowstart, csr2,
                                                 Wfb, bf, Wdb, zzb, zwb, Nn);

    // ---- adj = zw @ z^T ----
    int db = (Nn + 127) / 128;
    decode32_kernel<<<dim3(db, db), 256, 0, stream>>>(zwb, zzb, (float*)d_out, Nn);
}

// Round 10
// 318.126 us; speedup vs baseline: 1.0490x; 1.0490x over previous
//
#include <hip/hip_runtime.h>
#include <hip/hip_bf16.h>
#include <cstdint>
#include <cstddef>

// ---------------------------------------------------------------------------
// GraphAutoEncoder: 3x TAGConv(K=3) + linear + bilinear decode.
// N=10000, E=320000, D: 256 -> 128 -> 128 -> 64.
// Round 9: R8 structure with the scan int4 bug reverted (scalar scan —
// chunk=10 isn't a multiple of 4; the vector path double-counted neighbors
// and was misaligned). 3-deep gather pipeline + yk prefetch + fp32-x proj.
// ---------------------------------------------------------------------------

typedef __attribute__((ext_vector_type(8)))  short short8;   // 8 bf16
typedef __attribute__((ext_vector_type(4)))  float f32x4;
typedef __attribute__((ext_vector_type(16))) float f32x16;

static __device__ __forceinline__ ushort f2bf(float f) {
    __hip_bfloat16 h = __float2bfloat16(f);
    return *reinterpret_cast<const ushort*>(&h);
}
static __device__ __forceinline__ float bf2f(ushort u) {
    union { uint i; float f; } v; v.i = ((uint)u) << 16; return v.f;
}

// ---------------- setup: edge count + weight prep (fused) ----------

static __device__ __forceinline__ void prep_w_elem(const float* W, ushort* Wp,
                                                   int DIN, int DOUT, int i) {
    int hp  = i / (DIN * DOUT);
    int rem = i - hp * DIN * DOUT;
    int d   = rem / DOUT;
    int o   = rem - d * DOUT;
    Wp[(size_t)(hp * DOUT + o) * DIN + d] = f2bf(W[i]);
}
static __device__ __forceinline__ void prep_wt_elem(const float* W, ushort* Wt,
                                                    int K, int C, int i) {
    int k = i / C, c = i - k * C;
    Wt[(size_t)c * K + k] = f2bf(W[i]);
}

__global__ void setup_kernel(const int* __restrict__ dst, int* __restrict__ counts, int E,
                             const float* __restrict__ W1, ushort* __restrict__ Wp1,
                             const float* __restrict__ W2, ushort* __restrict__ Wp2,
                             const float* __restrict__ W3, ushort* __restrict__ Wp3,
                             const float* __restrict__ Wf, ushort* __restrict__ Wfb,
                             const float* __restrict__ Wd, ushort* __restrict__ Wdb) {
    const int n1 = 4 * 256 * 128, n2 = 4 * 128 * 128, n3 = 4 * 128 * 64, nf = 64 * 64;
    int i = blockIdx.x * blockDim.x + threadIdx.x;
    if (i < E) atomicAdd(&counts[dst[i]], 1);
    if (i < n1) { prep_w_elem(W1, Wp1, 256, 128, i); return; }
    int j = i - n1;
    if (j < n2) { prep_w_elem(W2, Wp2, 128, 128, j); return; }
    j -= n2;
    if (j < n3) { prep_w_elem(W3, Wp3, 128, 64, j); return; }
    j -= n3;
    if (j < nf) { prep_wt_elem(Wf, Wfb, 64, 64, j); return; }
    j -= nf;
    if (j < nf) { prep_wt_elem(Wd, Wdb, 64, 64, j); return; }
}

// exclusive scan counts[n] -> rowstart[n+1], plus dis[i] = rsqrt(deg)
__global__ void scan_kernel(const int* __restrict__ counts, int* __restrict__ rowstart,
                            float* __restrict__ dis, int n) {
    __shared__ int sums[1024];
    int t = threadIdx.x;
    int chunk = (n + 1023) / 1024;
    int base = t * chunk;
    int s = 0;
    for (int i = 0; i < chunk; ++i) {
        int idx = base + i;
        if (idx < n) s += counts[idx];
    }
    sums[t] = s;
    __syncthreads();
    for (int off = 1; off < 1024; off <<= 1) {
        int v = (t >= off) ? sums[t - off] : 0;
        __syncthreads();
        sums[t] += v;
        __syncthreads();
    }
    int run = sums[t] - s;
    for (int i = 0; i < chunk; ++i) {
        int idx = base + i;
        if (idx < n) {
            rowstart[idx] = run;
            int c = counts[idx];
            dis[idx] = (c > 0) ? rsqrtf((float)c) : 0.f;
            run += c;
        }
    }
    if (t == 1023) rowstart[n] = sums[1023];
}

// CSR fill, interleaved int2 (src, float_bits(w)); w = dis[src]*dis[dst]
__global__ void csr_fill_kernel(const int* __restrict__ src, const int* __restrict__ dst,
                                const float* __restrict__ dis, const int* __restrict__ rowstart,
                                int* __restrict__ cursor, int2* __restrict__ csr2, int E) {
    int e = blockIdx.x * blockDim.x + threadIdx.x;
    if (e < E) {
        int d = dst[e];
        int s = src[e];
        int pos = rowstart[d] + atomicAdd(&cursor[d], 1);
        csr2[pos] = make_int2(s, __float_as_int(dis[s] * dis[d]));
    }
}

// ---------------- layer-1 projection: fp32 x in, bf16 frags in-register -----
__global__ __launch_bounds__(256) void proj_gemm_x_kernel(
        const float* __restrict__ A, const ushort* __restrict__ Wp,
        const float* __restrict__ bias, ushort* __restrict__ y, int M) {
    constexpr int DIN = 256, DOUT = 128, NJ = 8;
    int tid = threadIdx.x, wave = tid >> 6, lane = tid & 63;
    int lr = lane & 15, lk = lane >> 4;
    int r0 = blockIdx.x * 32;
    int ra0 = min(r0 + lr, M - 1);
    int ra1 = min(r0 + 16 + lr, M - 1);

    f32x4 acc[2][NJ];
    #pragma unroll
    for (int mi = 0; mi < 2; ++mi)
        #pragma unroll
        for (int nj = 0; nj < NJ; ++nj)
            acc[mi][nj] = (f32x4){0.f, 0.f, 0.f, 0.f};

    const float* a0p = A + (size_t)ra0 * DIN + lk * 8;
    const float* a1p = A + (size_t)ra1 * DIN + lk * 8;
    #pragma unroll
    for (int kc = 0; kc < DIN; kc += 32) {
        float4 f00 = *(const float4*)(a0p + kc);
        float4 f01 = *(const float4*)(a0p + kc + 4);
        float4 f10 = *(const float4*)(a1p + kc);
        float4 f11 = *(const float4*)(a1p + kc + 4);
        short8 a0, a1;
        a0[0] = (short)f2bf(f00.x); a0[1] = (short)f2bf(f00.y);
        a0[2] = (short)f2bf(f00.z); a0[3] = (short)f2bf(f00.w);
        a0[4] = (short)f2bf(f01.x); a0[5] = (short)f2bf(f01.y);
        a0[6] = (short)f2bf(f01.z); a0[7] = (short)f2bf(f01.w);
        a1[0] = (short)f2bf(f10.x); a1[1] = (short)f2bf(f10.y);
        a1[2] = (short)f2bf(f10.z); a1[3] = (short)f2bf(f10.w);
        a1[4] = (short)f2bf(f11.x); a1[5] = (short)f2bf(f11.y);
        a1[6] = (short)f2bf(f11.z); a1[7] = (short)f2bf(f11.w);
        #pragma unroll
        for (int nj = 0; nj < NJ; ++nj) {
            short8 b = *(const short8*)(Wp + (size_t)(wave * DOUT + nj * 16 + lr) * DIN
                                        + kc + lk * 8);
            acc[0][nj] = __builtin_amdgcn_mfma_f32_16x16x32_bf16(a0, b, acc[0][nj], 0, 0, 0);
            acc[1][nj] = __builtin_amdgcn_mfma_f32_16x16x32_bf16(a1, b, acc[1][nj], 0, 0, 0);
        }
    }

    ushort* yw = y + (size_t)wave * M * DOUT;
    #pragma unroll
    for (int nj = 0; nj < NJ; ++nj) {
        int c = nj * 16 + lr;
        float bv = (wave == 0) ? bias[c] : 0.f;
        #pragma unroll
        for (int mi = 0; mi < 2; ++mi) {
            int rbase = r0 + mi * 16 + lk * 4;
            #pragma unroll
            for (int r = 0; r < 4; ++r) {
                int row = rbase + r;
                if (row < M)
                    yw[(size_t)row * DOUT + c] = f2bf(acc[mi][nj][r] + bv);
            }
        }
    }
}

// ---------------- projection GEMM: y_k = A @ W[k]^T (all 4 hops), bf16 ------
template <int DIN, int DOUT>
__global__ __launch_bounds__(256) void proj_gemm_kernel(
        const ushort* __restrict__ A, const ushort* __restrict__ Wp,
        const float* __restrict__ bias, ushort* __restrict__ y, int M) {
    constexpr int NJ = DOUT / 16;
    int tid = threadIdx.x, wave = tid >> 6, lane = tid & 63;
    int lr = lane & 15, lk = lane >> 4;
    int r0 = blockIdx.x * 32;
    int ra0 = min(r0 + lr, M - 1);
    int ra1 = min(r0 + 16 + lr, M - 1);

    f32x4 acc[2][NJ];
    #pragma unroll
    for (int mi = 0; mi < 2; ++mi)
        #pragma unroll
        for (int nj = 0; nj < NJ; ++nj)
            acc[mi][nj] = (f32x4){0.f, 0.f, 0.f, 0.f};

    const ushort* a0p = A + (size_t)ra0 * DIN + lk * 8;
    const ushort* a1p = A + (size_t)ra1 * DIN + lk * 8;
    #pragma unroll
    for (int kc = 0; kc < DIN; kc += 32) {
        short8 a0 = *(const short8*)(a0p + kc);
        short8 a1 = *(const short8*)(a1p + kc);
        #pragma unroll
        for (int nj = 0; nj < NJ; ++nj) {
            short8 b = *(const short8*)(Wp + (size_t)(wave * DOUT + nj * 16 + lr) * DIN
                                        + kc + lk * 8);
            acc[0][nj] = __builtin_amdgcn_mfma_f32_16x16x32_bf16(a0, b, acc[0][nj], 0, 0, 0);
            acc[1][nj] = __builtin_amdgcn_mfma_f32_16x16x32_bf16(a1, b, acc[1][nj], 0, 0, 0);
        }
    }

    ushort* yw = y + (size_t)wave * M * DOUT;
    #pragma unroll
    for (int nj = 0; nj < NJ; ++nj) {
        int c = nj * 16 + lr;
        float bv = (wave == 0) ? bias[c] : 0.f;
        #pragma unroll
        for (int mi = 0; mi < 2; ++mi) {
            int rbase = r0 + mi * 16 + lk * 4;
            #pragma unroll
            for (int r = 0; r < 4; ++r) {
                int row = rbase + r;
                if (row < M)
                    yw[(size_t)row * DOUT + c] = f2bf(acc[mi][nj][r] + bv);
            }
        }
    }
}

// ---------------- Horner aggregation: out = (yk + A*h) [relu] ---------------
// 512-thr blocks (8 nodes); wave-per-node; 3-deep pipelined gather
// (two loads in flight); yk loaded before the loop.
template <int D, bool RELU>
__global__ __launch_bounds__(512) void agg7_kernel(
        const ushort* __restrict__ h, const ushort* __restrict__ yk,
        const int* __restrict__ rowstart, const int2* __restrict__ csr2,
        ushort* __restrict__ out, int Nn) {
    constexpr int LPE = D / 8;        // 16 (D=128) or 8 (D=64)
    constexpr int EPI = 64 / LPE;     // 4 or 8
    int wave = threadIdx.x >> 6, lane = threadIdx.x & 63;
    int n = blockIdx.x * 8 + wave;
    if (n >= Nn) return;
    int sub = lane / LPE;
    int ll  = lane % LPE;
    int beg = rowstart[n], end = rowstart[n + 1];

    // prefetch the combine operand before the gather chain
    short8 yv = *(const short8*)(yk + (size_t)n * D + ll * 8);

    float acc[8];
    #pragma unroll
    for (int v = 0; v < 8; ++v) acc[v] = 0.f;

    for (int j0 = beg; j0 < end; j0 += 64) {
        int take = end - j0;
        if (take > 64) take = 64;
        int2 ed = make_int2(0, 0);
        if (lane < take) ed = csr2[j0 + lane];
        int   s = ed.x;
        float w = __int_as_float(ed.y);
        int tt = (take + EPI - 1) & ~(EPI - 1);
        int iters = tt / EPI;               // >= 1

        // 3-deep pipeline: compute stage 0 while stages 1,2 load
        float w0 = __shfl(w, sub);
        int   s0 = __shfl(s, sub);
        short8 h0 = *(const short8*)(h + (size_t)s0 * D + ll * 8);
        if (iters == 1) {
            #pragma unroll
            for (int v = 0; v < 8; ++v)
                acc[v] = fmaf(w0, bf2f((ushort)h0[v]), acc[v]);
            continue;
        }
        float w1 = __shfl(w, EPI + sub);
        int   s1 = __shfl(s, EPI + sub);
        short8 h1 = *(const short8*)(h + (size_t)s1 * D + ll * 8);
        for (int i = 2 * EPI; i < tt; i += EPI) {
            float w2 = __shfl(w, i + sub);
            int   s2 = __shfl(s, i + sub);
            short8 h2 = *(const short8*)(h + (size_t)s2 * D + ll * 8);
            #pragma unroll
            for (int v = 0; v < 8; ++v)
                acc[v] = fmaf(w0, bf2f((ushort)h0[v]), acc[v]);
            w0 = w1; h0 = h1;
            w1 = w2; h1 = h2;
        }
        #pragma unroll
        for (int v = 0; v < 8; ++v)
            acc[v] = fmaf(w0, bf2f((ushort)h0[v]), acc[v]);
        #pragma unroll
        for (int v = 0; v < 8; ++v)
            acc[v] = fmaf(w1, bf2f((ushort)h1[v]), acc[v]);
    }

    #pragma unroll
    for (int off = LPE; off < 64; off <<= 1) {
        #pragma unroll
        for (int v = 0; v < 8; ++v) acc[v] += __shfl_xor(acc[v], off);
    }

    if (sub == 0) {
        short8 o;
        #pragma unroll
        for (int v = 0; v < 8; ++v) {
            float val = acc[v] + bf2f((ushort)yv[v]);
            if (RELU) val = fmaxf(val, 0.f);
            o[v] = (short)f2bf(val);
        }
        *(short8*)(out + (size_t)n * D + ll * 8) = o;
    }
}

// ---------------- fused dual projection: zz = A@Wf^T+bf ; zw = zz@Wd^T ------
__global__ __launch_bounds__(256) void lin64_dual_kernel(
        const ushort* __restrict__ A, const ushort* __restrict__ Wfb,
        const float* __restrict__ bias, const ushort* __restrict__ Wdb,
        ushort* __restrict__ zz, ushort* __restrict__ zw, int M) {
    __shared__ ushort zl[4][32][72];   // +8 ushort pad
    int tid = threadIdx.x, wave = tid >> 6, lane = tid & 63;
    int lr = lane & 15, lk = lane >> 4;
    int r0 = blockIdx.x * 128 + wave * 32;
    int ra0 = min(r0 + lr, M - 1);
    int ra1 = min(r0 + 16 + lr, M - 1);

    short8 a[2][2], b[4][2];
    #pragma unroll
    for (int kc = 0; kc < 2; ++kc) {
        a[0][kc] = *(const short8*)(A + (size_t)ra0 * 64 + kc * 32 + lk * 8);
        a[1][kc] = *(const short8*)(A + (size_t)ra1 * 64 + kc * 32 + lk * 8);
        #pragma unroll
        for (int nj = 0; nj < 4; ++nj)
            b[nj][kc] = *(const short8*)(Wfb + (size_t)(nj * 16 + lr) * 64 + kc * 32 + lk * 8);
    }
    f32x4 acc1[2][4];
    #pragma unroll
    for (int mi = 0; mi < 2; ++mi)
        #pragma unroll
        for (int nj = 0; nj < 4; ++nj) {
            acc1[mi][nj] = (f32x4){0.f, 0.f, 0.f, 0.f};
            acc1[mi][nj] = __builtin_amdgcn_mfma_f32_16x16x32_bf16(a[mi][0], b[nj][0], acc1[mi][nj], 0, 0, 0);
            acc1[mi][nj] = __builtin_amdgcn_mfma_f32_16x16x32_bf16(a[mi][1], b[nj][1], acc1[mi][nj], 0, 0, 0);
        }

    #pragma unroll
    for (int nj = 0; nj < 4; ++nj) {
        int c = nj * 16 + lr;
        float bv = bias[c];
        #pragma unroll
        for (int mi = 0; mi < 2; ++mi) {
            int rloc = mi * 16 + lk * 4;
            #pragma unroll
            for (int r = 0; r < 4; ++r) {
                ushort u = f2bf(acc1[mi][nj][r] + bv);
                zl[wave][rloc + r][c] = u;
                int row = r0 + rloc + r;
                if (row < M) zz[(size_t)row * 64 + c] = u;
            }
        }
    }
    __syncthreads();

    short8 a2[2][2], b2[4][2];
    #pragma unroll
    for (int kc = 0; kc < 2; ++kc) {
        a2[0][kc] = *(const short8*)&zl[wave][lr][kc * 32 + lk * 8];
        a2[1][kc] = *(const short8*)&zl[wave][16 + lr][kc * 32 + lk * 8];
        #pragma unroll
        for (int nj = 0; nj < 4; ++nj)
            b2[nj][kc] = *(const short8*)(Wdb + (size_t)(nj * 16 + lr) * 64 + kc * 32 + lk * 8);
    }
    f32x4 acc2[2][4];
    #pragma unroll
    for (int mi = 0; mi < 2; ++mi)
        #pragma unroll
        for (int nj = 0; nj < 4; ++nj) {
            acc2[mi][nj] = (f32x4){0.f, 0.f, 0.f, 0.f};
            acc2[mi][nj] = __builtin_amdgcn_mfma_f32_16x16x32_bf16(a2[mi][0], b2[nj][0], acc2[mi][nj], 0, 0, 0);
            acc2[mi][nj] = __builtin_amdgcn_mfma_f32_16x16x32_bf16(a2[mi][1], b2[nj][1], acc2[mi][nj], 0, 0, 0);
        }
    #pragma unroll
    for (int nj = 0; nj < 4; ++nj) {
        int c = nj * 16 + lr;
        #pragma unroll
        for (int mi = 0; mi < 2; ++mi) {
            int rbase = r0 + mi * 16 + lk * 4;
            #pragma unroll
            for (int r = 0; r < 4; ++r) {
                int row = rbase + r;
                if (row < M) zw[(size_t)row * 64 + c] = f2bf(acc2[mi][nj][r]);
            }
        }
    }
}

// ---------------- decode: adj = ZW @ Z^T via 32x32x16 MFMA ----------------
__global__ __launch_bounds__(256) void decode32_kernel(
        const ushort* __restrict__ ZW, const ushort* __restrict__ Z,
        float* __restrict__ out, int Nn) {
    int tid = threadIdx.x, wave = tid >> 6, lane = tid & 63;
    int wr = wave >> 1, wc = wave & 1;
    int row0 = blockIdx.y * 128 + wr * 64;
    int col0 = blockIdx.x * 128 + wc * 64;
    int lr = lane & 31, hi = lane >> 5;

    short8 a[2][4], b[2][4];
    #pragma unroll
    for (int mi = 0; mi < 2; ++mi) {
        int ra = min(row0 + mi * 32 + lr, Nn - 1);
        int rb = min(col0 + mi * 32 + lr, Nn - 1);
        const ushort* pa = ZW + (size_t)ra * 64 + hi * 8;
        const ushort* pb = Z  + (size_t)rb * 64 + hi * 8;
        #pragma unroll
        for (int kc = 0; kc < 4; ++kc) {
            a[mi][kc] = *(const short8*)(pa + kc * 16);
            b[mi][kc] = *(const short8*)(pb + kc * 16);
        }
    }

    f32x16 acc[2][2];
    #pragma unroll
    for (int mi = 0; mi < 2; ++mi)
        #pragma unroll
        for (int nj = 0; nj < 2; ++nj) {
            f32x16 c;
            #pragma unroll
            for (int q = 0; q < 16; ++q) c[q] = 0.f;
            #pragma unroll
            for (int kc = 0; kc < 4; ++kc)
                c = __builtin_amdgcn_mfma_f32_32x32x16_bf16(a[mi][kc], b[nj][kc], c, 0, 0, 0);
            acc[mi][nj] = c;
        }

    bool full = (row0 + 64 <= Nn) && (col0 + 64 <= Nn);
    #pragma unroll
    for (int mi = 0; mi < 2; ++mi)
        #pragma unroll
        for (int nj = 0; nj < 2; ++nj) {
            int cb = col0 + nj * 32 + lr;
            #pragma unroll
            for (int reg = 0; reg < 16; ++reg) {
                int row = row0 + mi * 32 + (reg & 3) + 8 * (reg >> 2) + 4 * hi;
                if (full) {
                    __builtin_nontemporal_store(acc[mi][nj][reg], &out[(size_t)row * Nn + cb]);
                } else {
                    if (row < Nn && cb < Nn)
                        __builtin_nontemporal_store(acc[mi][nj][reg], &out[(size_t)row * Nn + cb]);
                }
            }
        }
}

// ---------------- launch ----------------

extern "C" void kernel_launch(void* const* d_in, const int* in_sizes, int n_in,
                              void* d_out, int out_size, void* d_ws, size_t ws_size,
                              hipStream_t stream) {
    const float* x  = (const float*)d_in[0];
    const int*   ei = (const int*)d_in[1];
    const float* W1 = (const float*)d_in[2];
    const float* b1 = (const float*)d_in[3];
    const float* W2 = (const float*)d_in[4];
    const float* b2 = (const float*)d_in[5];
    const float* W3 = (const float*)d_in[6];
    const float* b3 = (const float*)d_in[7];
    const float* Wf = (const float*)d_in[8];
    const float* bf = (const float*)d_in[9];
    const float* Wd = (const float*)d_in[10];

    const int Nn = in_sizes[0] / 256;   // 10000
    const int E  = in_sizes[1] / 2;     // 320000
    const int* src = ei;
    const int* dst = ei + E;

    char* p = (char*)d_ws;
    auto alloc = [&](size_t bytes) -> char* {
        char* r = p;
        p += (bytes + 255) & ~(size_t)255;
        return r;
    };
    size_t nslot = ((size_t)Nn * 4 + 255) & ~(size_t)255;
    int*    counts   = (int*)alloc((size_t)Nn * 4);
    int*    cursor   = (int*)alloc((size_t)Nn * 4);
    int*    rowstart = (int*)alloc((size_t)(Nn + 1) * 4);
    float*  dis      = (float*)alloc((size_t)Nn * 4);
    int2*   csr2     = (int2*)alloc((size_t)E * 8);
    ushort* yb       = (ushort*)alloc((size_t)4 * Nn * 128 * 2);  // y[4][Nn][<=128]
    ushort* t1       = (ushort*)alloc((size_t)Nn * 128 * 2);
    ushort* t2       = (ushort*)alloc((size_t)Nn * 128 * 2);
    ushort* out1b    = (ushort*)alloc((size_t)Nn * 128 * 2);
    ushort* out2b    = (ushort*)alloc((size_t)Nn * 128 * 2);
    ushort* out3b    = (ushort*)alloc((size_t)Nn * 64 * 2);
    ushort* zzb      = (ushort*)alloc((size_t)Nn * 64 * 2);
    ushort* zwb      = (ushort*)alloc((size_t)Nn * 64 * 2);
    ushort* Wp1      = (ushort*)alloc((size_t)512 * 256 * 2);
    ushort* Wp2      = (ushort*)alloc((size_t)512 * 128 * 2);
    ushort* Wp3      = (ushort*)alloc((size_t)256 * 128 * 2);
    ushort* Wfb      = (ushort*)alloc((size_t)64 * 64 * 2);
    ushort* Wdb      = (ushort*)alloc((size_t)64 * 64 * 2);

    hipMemsetAsync(counts, 0, nslot + (size_t)Nn * 4, stream);

    int nprep = 4 * 256 * 128 + 4 * 128 * 128 + 4 * 128 * 64 + 64 * 64 + 64 * 64;
    int nsetup = nprep > E ? nprep : E;
    setup_kernel<<<(nsetup + 255) / 256, 256, 0, stream>>>(
        dst, counts, E, W1, Wp1, W2, Wp2, W3, Wp3, Wf, Wfb, Wd, Wdb);

    scan_kernel<<<1, 1024, 0, stream>>>(counts, rowstart, dis, Nn);

    int eb = (E + 255) / 256;
    csr_fill_kernel<<<eb, 256, 0, stream>>>(src, dst, dis, rowstart, cursor, csr2, E);

    int ab = (Nn + 7) / 8;              // agg blocks (8 nodes, 512 thr)
    int gb = (Nn + 31) / 32;
    size_t Y128 = (size_t)Nn * 128;
    size_t Y64  = (size_t)Nn * 64;

    // ---- layer 1: 256 -> 128 (project fp32 x directly, Horner hops @128) ----
    proj_gemm_x_kernel<<<gb, 256, 0, stream>>>(x, Wp1, b1, yb, Nn);
    agg7_kernel<128, false><<<ab, 512, 0, stream>>>(yb + 3 * Y128, yb + 2 * Y128,
                                                    rowstart, csr2, t1, Nn);
    agg7_kernel<128, false><<<ab, 512, 0, stream>>>(t1, yb + 1 * Y128,
                                                    rowstart, csr2, t2, Nn);
    agg7_kernel<128, true ><<<ab, 512, 0, stream>>>(t2, yb,
                                                    rowstart, csr2, out1b, Nn);

    // ---- layer 2: 128 -> 128 ----
    proj_gemm_kernel<128, 128><<<gb, 256, 0, stream>>>(out1b, Wp2, b2, yb, Nn);
    agg7_kernel<128, false><<<ab, 512, 0, stream>>>(yb + 3 * Y128, yb + 2 * Y128,
                                                    rowstart, csr2, t1, Nn);
    agg7_kernel<128, false><<<ab, 512, 0, stream>>>(t1, yb + 1 * Y128,
                                                    rowstart, csr2, t2, Nn);
    agg7_kernel<128, true ><<<ab, 512, 0, stream>>>(t2, yb,
                                                    rowstart, csr2, out2b, Nn);

    // ---- layer 3: 128 -> 64 (hops at D=64) ----
    proj_gemm_kernel<128, 64><<<gb, 256, 0, stream>>>(out2b, Wp3, b3, yb, Nn);
    agg7_kernel<64, false><<<ab, 512, 0, stream>>>(yb + 3 * Y64, yb + 2 * Y64,
                                                   rowstart, csr2, t1, Nn);
    agg7_kernel<64, false><<<ab, 512, 0, stream>>>(t1, yb + 1 * Y64,
                                                   rowstart, csr2, t2, Nn);
    agg7_kernel<64, true ><<<ab, 512, 0, stream>>>(t2, yb,
                                                   rowstart, csr2, out3b, Nn);

    // ---- zz = h @ Wf + bf ; zw = zz @ Wd (fused) ----
    int lb = (Nn + 127) / 128;
    lin64_dual_kernel<<<lb, 256, 0, stream>>>(out3b, Wfb, bf, Wdb, zzb, zwb, Nn);

    // ---- adj = zw @ z^T ----
    int db = (Nn + 127) / 128;
    decode32_kernel<<<dim3(db, db), 256, 0, stream>>>(zwb, zzb, (float*)d_out, Nn);
}